// Round 1
// baseline (329.154 us; speedup 1.0000x reference)
//
#include <hip/hip_runtime.h>
#include <hip/hip_bf16.h>
#include <stdint.h>

#define B_N 16384
#define F_N 1024
#define D_N 4
#define O_N 32
#define NCOL1 (D_N * F_N) /* 4096 */
#define NCOL2 (D_N * O_N) /* 128  */

static constexpr float EPS = 1e-5f;

typedef __bf16 bf16x8 __attribute__((ext_vector_type(8)));
typedef __bf16 bf16x4 __attribute__((ext_vector_type(4)));
typedef float  f32x4  __attribute__((ext_vector_type(4)));

// global -> LDS async copy, 16B per lane. LDS dest must be wave-uniform base.
#define GLD16(gp, lp)                                                          \
  __builtin_amdgcn_global_load_lds(                                            \
      (__attribute__((address_space(1))) void*)(uintptr_t)(gp),                \
      (__attribute__((address_space(3))) void*)(lp), 16, 0, 0)

// ---------------- BN1 stats on x (per-column over batch) ----------------
// grid 128, block 256; each block reduces 128 rows; thread owns 4 cols.
__global__ __launch_bounds__(256) void k_stats_x_partial(
    const float* __restrict__ x, float* __restrict__ part) {
  int t = threadIdx.x, blk = blockIdx.x;
  const float4* xr = (const float4*)x;
  float s0 = 0, s1 = 0, s2 = 0, s3 = 0, q0 = 0, q1 = 0, q2 = 0, q3 = 0;
  int r0 = blk * 128;
  for (int r = r0; r < r0 + 128; ++r) {
    float4 v = xr[(size_t)r * (F_N / 4) + t];
    s0 += v.x; q0 += v.x * v.x;
    s1 += v.y; q1 += v.y * v.y;
    s2 += v.z; q2 += v.z * v.z;
    s3 += v.w; q3 += v.w * v.w;
  }
  float* p = part + (size_t)blk * 2048;
  p[t * 4 + 0] = s0; p[t * 4 + 1] = s1; p[t * 4 + 2] = s2; p[t * 4 + 3] = s3;
  p[1024 + t * 4 + 0] = q0; p[1024 + t * 4 + 1] = q1;
  p[1024 + t * 4 + 2] = q2; p[1024 + t * 4 + 3] = q3;
}

__global__ __launch_bounds__(256) void k_stats_x_final(
    const float* __restrict__ part, float* __restrict__ meanx,
    float* __restrict__ rstdx) {
  int c = blockIdx.x * 256 + threadIdx.x;
  float s = 0, q = 0;
  for (int b = 0; b < 128; ++b) {
    s += part[(size_t)b * 2048 + c];
    q += part[(size_t)b * 2048 + 1024 + c];
  }
  float mean = s * (1.0f / B_N);
  float var = q * (1.0f / B_N) - mean * mean;
  meanx[c] = mean;
  rstdx[c] = rsqrtf(var + EPS);
}

// ---------------- fold g1 into W1, convert to bf16 ----------------
__global__ __launch_bounds__(256) void k_fold_w1(const float* __restrict__ W1,
                                                 const float* __restrict__ g1,
                                                 __bf16* __restrict__ W1b) {
  size_t base = (size_t)(blockIdx.x * 256 + threadIdx.x) * 4;
  int f = (int)(base & (F_N - 1));
  int d = (int)(base >> 20);
  float4 w = *(const float4*)(W1 + base);
  float4 g = *(const float4*)(g1 + d * F_N + f);
  bf16x4 o;
  o[0] = (__bf16)(w.x * g.x); o[1] = (__bf16)(w.y * g.y);
  o[2] = (__bf16)(w.z * g.z); o[3] = (__bf16)(w.w * g.w);
  *(bf16x4*)(W1b + base) = o;
}

__global__ __launch_bounds__(256) void k_fold_w2(const float* __restrict__ W2,
                                                 __bf16* __restrict__ W2b) {
  size_t base = (size_t)(blockIdx.x * 256 + threadIdx.x) * 4;
  float4 w = *(const float4*)(W2 + base);
  bf16x4 o;
  o[0] = (__bf16)w.x; o[1] = (__bf16)w.y; o[2] = (__bf16)w.z; o[3] = (__bf16)w.w;
  *(bf16x4*)(W2b + base) = o;
}

// ---------------- xn = (x - mean)*rstd, bf16 ----------------
__global__ __launch_bounds__(256) void k_make_xn(const float* __restrict__ x,
                                                 const float* __restrict__ meanx,
                                                 const float* __restrict__ rstdx,
                                                 __bf16* __restrict__ xn) {
  size_t base = (size_t)(blockIdx.x * 256 + threadIdx.x) * 4;
  int f = (int)(base & (F_N - 1));
  float4 v = *(const float4*)(x + base);
  float4 m = *(const float4*)(meanx + f);
  float4 r = *(const float4*)(rstdx + f);
  bf16x4 o;
  o[0] = (__bf16)((v.x - m.x) * r.x);
  o[1] = (__bf16)((v.y - m.y) * r.y);
  o[2] = (__bf16)((v.z - m.z) * r.z);
  o[3] = (__bf16)((v.w - m.w) * r.w);
  *(bf16x4*)(xn + base) = o;
}

// ---------------- GEMM1: G1[16384][4096] = xn @ W1b^T (bf16 in, bf16 out) ---
// m97 structure: 128x128 tile, BK=32, 4 waves, global_load_lds width 16.
__global__ __launch_bounds__(256) void k_gemm1(const __bf16* __restrict__ A,
                                               const __bf16* __restrict__ Bw,
                                               __bf16* __restrict__ C) {
  __shared__ __bf16 Asm[128 * 32];
  __shared__ __bf16 Bsm[128 * 32];
  const int tid = threadIdx.x;
  const int wave = tid >> 6, lane = tid & 63;
  const int m0 = blockIdx.x * 128, n0 = blockIdx.y * 128;
  // staging map: linear byte off = i*4096 + tid*16 -> row = i*64 + tid/4, colb=(tid%4)*16
  const int srow = tid >> 2;
  const int scol = (tid & 3) * 8;
  const __bf16* Ag = A + (size_t)(m0 + srow) * F_N + scol;
  const __bf16* Bg = Bw + (size_t)(n0 + srow) * F_N + scol;
  __bf16* AsBase = &Asm[wave * 512];
  __bf16* BsBase = &Bsm[wave * 512];
  const int fr = lane & 15, fk = (lane >> 4) * 8;
  const int awr = (wave >> 1) * 64, awc = (wave & 1) * 64;
  f32x4 acc[4][4] = {};
  for (int k0 = 0; k0 < F_N; k0 += 32) {
    __syncthreads();
    GLD16(Ag + k0, AsBase);
    GLD16(Ag + (size_t)64 * F_N + k0, AsBase + 2048);
    GLD16(Bg + k0, BsBase);
    GLD16(Bg + (size_t)64 * F_N + k0, BsBase + 2048);
    __syncthreads();
    bf16x8 af[4], bfr[4];
#pragma unroll
    for (int mi = 0; mi < 4; ++mi)
      af[mi] = *(const bf16x8*)&Asm[(awr + mi * 16 + fr) * 32 + fk];
#pragma unroll
    for (int ni = 0; ni < 4; ++ni)
      bfr[ni] = *(const bf16x8*)&Bsm[(awc + ni * 16 + fr) * 32 + fk];
#pragma unroll
    for (int mi = 0; mi < 4; ++mi)
#pragma unroll
      for (int ni = 0; ni < 4; ++ni)
        acc[mi][ni] = __builtin_amdgcn_mfma_f32_16x16x32_bf16(
            af[mi], bfr[ni], acc[mi][ni], 0, 0, 0);
  }
  const int cr = (lane >> 4) * 4, cc = lane & 15;
#pragma unroll
  for (int mi = 0; mi < 4; ++mi)
#pragma unroll
    for (int ni = 0; ni < 4; ++ni) {
      int row = m0 + awr + mi * 16 + cr;
      int col = n0 + awc + ni * 16 + cc;
#pragma unroll
      for (int r = 0; r < 4; ++r)
        C[(size_t)(row + r) * NCOL1 + col] = (__bf16)acc[mi][ni][r];
    }
}

// ---------------- BN2 stats on G1 ----------------
__global__ __launch_bounds__(256) void k_stats2_partial(
    const __bf16* __restrict__ G1, float* __restrict__ part) {
  int t = threadIdx.x, blk = blockIdx.x;
  float s[16], q[16];
#pragma unroll
  for (int j = 0; j < 16; ++j) { s[j] = 0; q[j] = 0; }
  int r0 = blk * 128;
  for (int r = r0; r < r0 + 128; ++r) {
    const __bf16* row = G1 + (size_t)r * NCOL1 + t * 16;
    bf16x8 v0 = *(const bf16x8*)row;
    bf16x8 v1 = *(const bf16x8*)(row + 8);
#pragma unroll
    for (int j = 0; j < 8; ++j) { float f = (float)v0[j]; s[j] += f; q[j] += f * f; }
#pragma unroll
    for (int j = 0; j < 8; ++j) { float f = (float)v1[j]; s[8 + j] += f; q[8 + j] += f * f; }
  }
  float* p = part + (size_t)blk * 8192;
#pragma unroll
  for (int j = 0; j < 16; ++j) {
    p[t * 16 + j] = s[j];
    p[4096 + t * 16 + j] = q[j];
  }
}

__global__ __launch_bounds__(256) void k_stats2_final(
    const float* __restrict__ part, const float* __restrict__ g2,
    const float* __restrict__ b2, float* __restrict__ a2,
    float* __restrict__ c2) {
  int c = blockIdx.x * 256 + threadIdx.x;
  float s = 0, q = 0;
  for (int b = 0; b < 128; ++b) {
    s += part[(size_t)b * 8192 + c];
    q += part[(size_t)b * 8192 + 4096 + c];
  }
  float mean = s * (1.0f / B_N);
  float var = q * (1.0f / B_N) - mean * mean;
  float rstd = rsqrtf(var + EPS);
  float aa = rstd * g2[c];
  a2[c] = aa;
  c2[c] = b2[c] - mean * aa;
}

// ---------------- GEMM2 fused: out2 = sigmoid(G1*a2+c2) @ W2b^T ----------
// grid (256, 4): 64 rows per block, one ensemble member d per blockIdx.y.
__global__ __launch_bounds__(256) void k_gemm2(
    const __bf16* __restrict__ G1, const __bf16* __restrict__ W2b,
    const float* __restrict__ a2, const float* __restrict__ c2,
    float* __restrict__ out2) {
  const int tid = threadIdx.x;
  const int wave = tid >> 6, lane = tid & 63;
  const int m0 = blockIdx.x * 64;
  const int d = blockIdx.y;
  const int fr = lane & 15, fk = (lane >> 4) * 8;
  const __bf16* Arow = G1 + (size_t)(m0 + wave * 16 + fr) * NCOL1 + d * F_N;
  const __bf16* Wd = W2b + (size_t)d * O_N * F_N;
  const float* ap = a2 + d * F_N;
  const float* cp = c2 + d * F_N;
  f32x4 acc[2] = {};
  for (int k0 = 0; k0 < F_N; k0 += 32) {
    bf16x8 av = *(const bf16x8*)(Arow + k0 + fk);
    f32x4 aa0 = *(const f32x4*)(ap + k0 + fk);
    f32x4 aa1 = *(const f32x4*)(ap + k0 + fk + 4);
    f32x4 cc0 = *(const f32x4*)(cp + k0 + fk);
    f32x4 cc1 = *(const f32x4*)(cp + k0 + fk + 4);
    bf16x8 af;
#pragma unroll
    for (int j = 0; j < 4; ++j) {
      float v = (float)av[j] * aa0[j] + cc0[j];
      af[j] = (__bf16)(1.0f / (1.0f + __expf(-v)));
    }
#pragma unroll
    for (int j = 0; j < 4; ++j) {
      float v = (float)av[4 + j] * aa1[j] + cc1[j];
      af[4 + j] = (__bf16)(1.0f / (1.0f + __expf(-v)));
    }
    bf16x8 b0 = *(const bf16x8*)(Wd + (size_t)fr * F_N + k0 + fk);
    bf16x8 b1 = *(const bf16x8*)(Wd + (size_t)(16 + fr) * F_N + k0 + fk);
    acc[0] = __builtin_amdgcn_mfma_f32_16x16x32_bf16(af, b0, acc[0], 0, 0, 0);
    acc[1] = __builtin_amdgcn_mfma_f32_16x16x32_bf16(af, b1, acc[1], 0, 0, 0);
  }
  const int cr = (lane >> 4) * 4, cc = lane & 15;
#pragma unroll
  for (int n = 0; n < 2; ++n)
#pragma unroll
    for (int r = 0; r < 4; ++r)
      out2[(size_t)(m0 + wave * 16 + cr + r) * NCOL2 + d * O_N + n * 16 + cc] =
          acc[n][r];
}

// ---------------- BN3 stats on out2 ----------------
__global__ __launch_bounds__(128) void k_stats3_partial(
    const float* __restrict__ out2, float* __restrict__ part) {
  int t = threadIdx.x, blk = blockIdx.x;
  float s = 0, q = 0;
  int r0 = blk * 128;
  for (int r = r0; r < r0 + 128; ++r) {
    float v = out2[(size_t)r * NCOL2 + t];
    s += v;
    q += v * v;
  }
  part[(size_t)blk * 256 + t] = s;
  part[(size_t)blk * 256 + 128 + t] = q;
}

__global__ __launch_bounds__(128) void k_stats3_final(
    const float* __restrict__ part, const float* __restrict__ g3,
    const float* __restrict__ b3, float* __restrict__ a3,
    float* __restrict__ c3) {
  int c = threadIdx.x;
  float s = 0, q = 0;
  for (int b = 0; b < 128; ++b) {
    s += part[(size_t)b * 256 + c];
    q += part[(size_t)b * 256 + 128 + c];
  }
  float mean = s * (1.0f / B_N);
  float var = q * (1.0f / B_N) - mean * mean;
  float rstd = rsqrtf(var + EPS);
  float aa = rstd * g3[c];
  a3[c] = aa;
  c3[c] = b3[c] - mean * aa;
}

// ---------------- final: out = sigmoid(out2*a3+c3) ----------------
__global__ __launch_bounds__(256) void k_final(const float* __restrict__ out2,
                                               const float* __restrict__ a3,
                                               const float* __restrict__ c3,
                                               float* __restrict__ out) {
  size_t base = (size_t)(blockIdx.x * 256 + threadIdx.x) * 4;
  int c = (int)(base & (NCOL2 - 1));
  f32x4 v = *(const f32x4*)(out2 + base);
  f32x4 a = *(const f32x4*)(a3 + c);
  f32x4 cc = *(const f32x4*)(c3 + c);
  f32x4 o;
#pragma unroll
  for (int j = 0; j < 4; ++j)
    o[j] = 1.0f / (1.0f + __expf(-(v[j] * a[j] + cc[j])));
  *(f32x4*)(out + base) = o;
}

extern "C" void kernel_launch(void* const* d_in, const int* in_sizes, int n_in,
                              void* d_out, int out_size, void* d_ws,
                              size_t ws_size, hipStream_t stream) {
  (void)in_sizes; (void)n_in; (void)out_size; (void)ws_size;
  const float* x = (const float*)d_in[0];
  const float* W1 = (const float*)d_in[1];
  const float* W2 = (const float*)d_in[2];
  const float* g1 = (const float*)d_in[3];
  // d_in[4] = b1: per-column constant after GEMM1, annihilated by BN2 mean-sub.
  const float* g2 = (const float*)d_in[5];
  const float* b2 = (const float*)d_in[6];
  const float* g3 = (const float*)d_in[7];
  const float* b3 = (const float*)d_in[8];
  float* out = (float*)d_out;

  char* ws = (char*)d_ws;
  size_t off = 0;
  auto alloc = [&](size_t bytes) -> void* {
    void* p = ws + off;
    off = (off + bytes + 255) & ~(size_t)255;
    return p;
  };
  float* meanx = (float*)alloc((size_t)F_N * 4);
  float* rstdx = (float*)alloc((size_t)F_N * 4);
  float* a2 = (float*)alloc((size_t)NCOL1 * 4);
  float* c2 = (float*)alloc((size_t)NCOL1 * 4);
  float* a3 = (float*)alloc((size_t)NCOL2 * 4);
  float* c3 = (float*)alloc((size_t)NCOL2 * 4);
  float* part1 = (float*)alloc((size_t)128 * 2048 * 4);
  float* part2 = (float*)alloc((size_t)128 * 8192 * 4);
  float* part3 = (float*)alloc((size_t)128 * 256 * 4);
  __bf16* W1b = (__bf16*)alloc((size_t)D_N * F_N * F_N * 2);
  __bf16* W2b = (__bf16*)alloc((size_t)D_N * O_N * F_N * 2);
  __bf16* xn = (__bf16*)alloc((size_t)B_N * F_N * 2);
  __bf16* G1 = (__bf16*)alloc((size_t)B_N * NCOL1 * 2);
  float* out2 = (float*)alloc((size_t)B_N * NCOL2 * 4);

  k_stats_x_partial<<<128, 256, 0, stream>>>(x, part1);
  k_stats_x_final<<<4, 256, 0, stream>>>(part1, meanx, rstdx);
  k_fold_w1<<<4096, 256, 0, stream>>>(W1, g1, W1b);
  k_fold_w2<<<128, 256, 0, stream>>>(W2, W2b);
  k_make_xn<<<16384, 256, 0, stream>>>(x, meanx, rstdx, xn);
  k_gemm1<<<dim3(128, 32), 256, 0, stream>>>(xn, W1b, G1);
  k_stats2_partial<<<128, 256, 0, stream>>>(G1, part2);
  k_stats2_final<<<16, 256, 0, stream>>>(part2, g2, b2, a2, c2);
  k_gemm2<<<dim3(256, 4), 256, 0, stream>>>(G1, W2b, a2, c2, out2);
  k_stats3_partial<<<128, 128, 0, stream>>>(out2, part3);
  k_stats3_final<<<1, 128, 0, stream>>>(part3, g3, b3, a3, c3);
  k_final<<<2048, 256, 0, stream>>>(out2, a3, c3, out);
}

// Round 2
// 303.690 us; speedup vs baseline: 1.0838x; 1.0838x over previous
//
#include <hip/hip_runtime.h>
#include <hip/hip_bf16.h>
#include <stdint.h>

#define B_N 16384
#define F_N 1024
#define D_N 4
#define O_N 32
#define NCOL1 (D_N * F_N) /* 4096 */
#define NCOL2 (D_N * O_N) /* 128  */

static constexpr float EPS = 1e-5f;

typedef __bf16 bf16x8 __attribute__((ext_vector_type(8)));
typedef __bf16 bf16x4 __attribute__((ext_vector_type(4)));
typedef float  f32x4  __attribute__((ext_vector_type(4)));

// global -> LDS async copy, 16B per lane. LDS dest must be wave-uniform base.
#define GLD16(gp, lp)                                                          \
  __builtin_amdgcn_global_load_lds(                                            \
      (__attribute__((address_space(1))) void*)(uintptr_t)(gp),                \
      (__attribute__((address_space(3))) void*)(lp), 16, 0, 0)

// ---------------- BN1 stats on x + convert x->bf16 (fused, one pass) -------
// No mean subtraction / no rstd applied to x: rstd folds into W1, the mean
// shift is annihilated by BN2's mean subtraction.
__global__ __launch_bounds__(256) void k_stats_x_conv(
    const float* __restrict__ x, float* __restrict__ part,
    __bf16* __restrict__ xb) {
  int t = threadIdx.x, blk = blockIdx.x;
  const float4* xr = (const float4*)x;
  float s0 = 0, s1 = 0, s2 = 0, s3 = 0, q0 = 0, q1 = 0, q2 = 0, q3 = 0;
  int r0 = blk * 128;
  for (int r = r0; r < r0 + 128; ++r) {
    float4 v = xr[(size_t)r * (F_N / 4) + t];
    s0 += v.x; q0 += v.x * v.x;
    s1 += v.y; q1 += v.y * v.y;
    s2 += v.z; q2 += v.z * v.z;
    s3 += v.w; q3 += v.w * v.w;
    bf16x4 o;
    o[0] = (__bf16)v.x; o[1] = (__bf16)v.y; o[2] = (__bf16)v.z; o[3] = (__bf16)v.w;
    *(bf16x4*)(xb + (size_t)r * F_N + t * 4) = o;
  }
  float* p = part + (size_t)blk * 2048;
  p[t * 4 + 0] = s0; p[t * 4 + 1] = s1; p[t * 4 + 2] = s2; p[t * 4 + 3] = s3;
  p[1024 + t * 4 + 0] = q0; p[1024 + t * 4 + 1] = q1;
  p[1024 + t * 4 + 2] = q2; p[1024 + t * 4 + 3] = q3;
}

__global__ __launch_bounds__(256) void k_stats_x_final(
    const float* __restrict__ part, float* __restrict__ rstdx) {
  int c = blockIdx.x * 256 + threadIdx.x;
  float s = 0, q = 0;
  for (int b = 0; b < 128; ++b) {
    s += part[(size_t)b * 2048 + c];
    q += part[(size_t)b * 2048 + 1024 + c];
  }
  float mean = s * (1.0f / B_N);
  float var = q * (1.0f / B_N) - mean * mean;
  rstdx[c] = rsqrtf(var + EPS);
}

// ---------------- fold g1 * rstd1 into W1, convert to bf16 ----------------
__global__ __launch_bounds__(256) void k_fold_w1(const float* __restrict__ W1,
                                                 const float* __restrict__ g1,
                                                 const float* __restrict__ rstdx,
                                                 __bf16* __restrict__ W1b) {
  size_t base = (size_t)(blockIdx.x * 256 + threadIdx.x) * 4;
  int f = (int)(base & (F_N - 1));
  int d = (int)(base >> 20);
  float4 w = *(const float4*)(W1 + base);
  float4 g = *(const float4*)(g1 + d * F_N + f);
  float4 r = *(const float4*)(rstdx + f);
  bf16x4 o;
  o[0] = (__bf16)(w.x * g.x * r.x); o[1] = (__bf16)(w.y * g.y * r.y);
  o[2] = (__bf16)(w.z * g.z * r.z); o[3] = (__bf16)(w.w * g.w * r.w);
  *(bf16x4*)(W1b + base) = o;
}

__global__ __launch_bounds__(256) void k_fold_w2(const float* __restrict__ W2,
                                                 __bf16* __restrict__ W2b) {
  size_t base = (size_t)(blockIdx.x * 256 + threadIdx.x) * 4;
  float4 w = *(const float4*)(W2 + base);
  bf16x4 o;
  o[0] = (__bf16)w.x; o[1] = (__bf16)w.y; o[2] = (__bf16)w.z; o[3] = (__bf16)w.w;
  *(bf16x4*)(W2b + base) = o;
}

// ---------------- GEMM1: G1[16384][4096] = xb @ W1b^T, 256^2 8-phase -------
// BM=BN=256, BK=64 (two K-halves of 32), 8 waves (2M x 4N), 128 KiB LDS.
// K-half LDS layout [256][32] (64B rows) is bank-optimal for the frag read
// pattern (16 rows x 4 16B-slots alternate bank halves) -> no swizzle needed.
// Counted vmcnt(4) at phases 2/4 of each K-tile; never drained in the loop.
// Epilogue: C write (bf16) + per-block BN2 column partial sums.
__global__ __launch_bounds__(512, 2) void k_gemm1(
    const __bf16* __restrict__ A, const __bf16* __restrict__ Bw,
    __bf16* __restrict__ C, float* __restrict__ p2s, float* __restrict__ p2q) {
  __shared__ __bf16 ldsA[2][2][256 * 32];
  __shared__ __bf16 ldsB[2][2][256 * 32];
  const int tid = threadIdx.x;
  const int wave = tid >> 6, lane = tid & 63;
  const int wm = wave >> 2, wn = wave & 3;
  // XCD-aware bijective swizzle: nwg=1024 divisible by 8.
  int bid = (int)blockIdx.x;
  int swz = (bid & 7) * 128 + (bid >> 3);
  const int bm = swz & 63, bn = swz >> 6; // 64 x 16
  const int m0 = bm * 256, n0 = bn * 256;
  const int fr = lane & 15, kg = lane >> 4;
  // staging source addressing: 512 thr x 16B = 8KB per round, 2 rounds/half
  const int srow = tid >> 2;           // 0..127
  const int scb = (tid & 3) * 16;      // byte col within 64B K-half row
  const char* Ab = (const char*)A + (size_t)(m0 + srow) * (F_N * 2) + scb;
  const char* Bb = (const char*)Bw + (size_t)(n0 + srow) * (F_N * 2) + scb;
  char* ldsAx = (char*)&ldsA[0][0][0];
  char* ldsBx = (char*)&ldsB[0][0][0];
  const int wo = wave * 1024;

#define SA(buf_, kk_, kb_)                                                     \
  do {                                                                         \
    GLD16(Ab + (kb_) + (kk_) * 64,                                             \
          ldsAx + (buf_) * 32768 + (kk_) * 16384 + wo);                        \
    GLD16(Ab + 128 * (F_N * 2) + (kb_) + (kk_) * 64,                           \
          ldsAx + (buf_) * 32768 + (kk_) * 16384 + 8192 + wo);                 \
  } while (0)
#define SBv(buf_, kk_, kb_)                                                    \
  do {                                                                         \
    GLD16(Bb + (kb_) + (kk_) * 64,                                             \
          ldsBx + (buf_) * 32768 + (kk_) * 16384 + wo);                        \
    GLD16(Bb + 128 * (F_N * 2) + (kb_) + (kk_) * 64,                           \
          ldsBx + (buf_) * 32768 + (kk_) * 16384 + 8192 + wo);                 \
  } while (0)
#define LDA4(buf_, kk_, qm_)                                                   \
  { _Pragma("unroll") for (int i_ = 0; i_ < 4; ++i_)                           \
      afr[i_] = *(const bf16x8*)&ldsA[buf_][kk_]                               \
          [(wm * 128 + (qm_) * 64 + i_ * 16 + fr) * 32 + kg * 8]; }
#define LDB4(buf_, kk_)                                                        \
  { _Pragma("unroll") for (int i_ = 0; i_ < 4; ++i_)                           \
      bfr[i_] = *(const bf16x8*)&ldsB[buf_][kk_]                               \
          [(wn * 64 + i_ * 16 + fr) * 32 + kg * 8]; }
#define MFMA16(qm_)                                                            \
  { _Pragma("unroll") for (int i_ = 0; i_ < 4; ++i_)                           \
      _Pragma("unroll") for (int j_ = 0; j_ < 4; ++j_)                         \
        acc[(qm_) * 4 + i_][j_] = __builtin_amdgcn_mfma_f32_16x16x32_bf16(     \
            afr[i_], bfr[j_], acc[(qm_) * 4 + i_][j_], 0, 0, 0); }
#define BAR() __builtin_amdgcn_s_barrier()
#define WAITLGKM()                                                             \
  do {                                                                         \
    asm volatile("s_waitcnt lgkmcnt(0)" ::: "memory");                         \
    __builtin_amdgcn_sched_barrier(0);                                         \
  } while (0)
#define WAITVM4() asm volatile("s_waitcnt vmcnt(4)" ::: "memory")
#define PRIO1() __builtin_amdgcn_s_setprio(1)
#define PRIO0() __builtin_amdgcn_s_setprio(0)

  f32x4 acc[8][4] = {};
  bf16x8 afr[4], bfr[4];

  // prologue: tile 0 halves in stream order B-K0, A-K0, B-K1, A-K1
  SBv(0, 0, 0); SA(0, 0, 0); SBv(0, 1, 0); SA(0, 1, 0);
  asm volatile("s_waitcnt vmcnt(4)" ::: "memory");
  BAR();

  // 16 K-tiles, 2 per iteration (8 phases). Tile t reads buf t&1; phases
  // stage tile t+1's halves into buf (t+1)&1 in order BK0,AK0,BK1,AK1.
  for (int t = 0; t < 16; t += 2) {
    const int kn1 = (t + 1) * 128;                     // byte offset of K-tile t+1
    const int kn2 = (t + 2 < 16) ? (t + 2) * 128 : 0;  // dummy clamp on tail
    // tile t (buf 0)
    LDA4(0, 0, 0); LDB4(0, 0); SBv(1, 0, kn1); BAR(); WAITLGKM(); PRIO1(); MFMA16(0); PRIO0(); BAR();
    LDA4(0, 0, 1);             SA (1, 0, kn1); BAR(); WAITLGKM(); PRIO1(); MFMA16(1); PRIO0(); WAITVM4(); BAR();
    LDA4(0, 1, 0); LDB4(0, 1); SBv(1, 1, kn1); BAR(); WAITLGKM(); PRIO1(); MFMA16(0); PRIO0(); BAR();
    LDA4(0, 1, 1);             SA (1, 1, kn1); BAR(); WAITLGKM(); PRIO1(); MFMA16(1); PRIO0(); WAITVM4(); BAR();
    // tile t+1 (buf 1)
    LDA4(1, 0, 0); LDB4(1, 0); SBv(0, 0, kn2); BAR(); WAITLGKM(); PRIO1(); MFMA16(0); PRIO0(); BAR();
    LDA4(1, 0, 1);             SA (0, 0, kn2); BAR(); WAITLGKM(); PRIO1(); MFMA16(1); PRIO0(); WAITVM4(); BAR();
    LDA4(1, 1, 0); LDB4(1, 1); SBv(0, 1, kn2); BAR(); WAITLGKM(); PRIO1(); MFMA16(0); PRIO0(); BAR();
    LDA4(1, 1, 1);             SA (0, 1, kn2); BAR(); WAITLGKM(); PRIO1(); MFMA16(1); PRIO0(); WAITVM4(); BAR();
  }

  // ---- epilogue: C write ----
  const int cr = kg * 4, cc = fr;
#pragma unroll
  for (int mi = 0; mi < 8; ++mi)
#pragma unroll
    for (int ni = 0; ni < 4; ++ni) {
      int row = m0 + wm * 128 + mi * 16 + cr;
      int col = n0 + wn * 64 + ni * 16 + cc;
#pragma unroll
      for (int r = 0; r < 4; ++r)
        C[(size_t)(row + r) * NCOL1 + col] = (__bf16)acc[mi][ni][r];
    }

  // ---- epilogue: BN2 per-block column partial sums (from f32 acc) ----
  // Overlay small reduce buffer on ldsA[1][0] (not touched by in-flight
  // tail dummy stages, which target buf 0 only; last reads were tile 15 ph2).
  float* srs = (float*)&ldsA[1][0][0];
  float* srq = srs + 512;
  __syncthreads();
#pragma unroll
  for (int ni = 0; ni < 4; ++ni) {
    float ss = 0, qq = 0;
#pragma unroll
    for (int mi = 0; mi < 8; ++mi) {
      f32x4 v = acc[mi][ni];
#pragma unroll
      for (int r = 0; r < 4; ++r) { ss += v[r]; qq += v[r] * v[r]; }
    }
    ss += __shfl_xor(ss, 16); ss += __shfl_xor(ss, 32);
    qq += __shfl_xor(qq, 16); qq += __shfl_xor(qq, 32);
    if (lane < 16) {
      srs[wave * 64 + ni * 16 + lane] = ss;
      srq[wave * 64 + ni * 16 + lane] = qq;
    }
  }
  __syncthreads();
  if (tid < 256) {
    int j = tid, wnn = j >> 6, jj = j & 63;
    float S = srs[wnn * 64 + jj] + srs[(4 + wnn) * 64 + jj];
    float Q = srq[wnn * 64 + jj] + srq[(4 + wnn) * 64 + jj];
    p2s[(size_t)bm * NCOL1 + n0 + j] = S;
    p2q[(size_t)bm * NCOL1 + n0 + j] = Q;
  }
#undef SA
#undef SBv
#undef LDA4
#undef LDB4
#undef MFMA16
#undef BAR
#undef WAITLGKM
#undef WAITVM4
#undef PRIO1
#undef PRIO0
}

// ---------------- BN2 finalize from per-block partials ----------------
__global__ __launch_bounds__(256) void k_stats2_final(
    const float* __restrict__ p2s, const float* __restrict__ p2q,
    const float* __restrict__ g2, const float* __restrict__ b2,
    float* __restrict__ a2, float* __restrict__ c2) {
  int c = blockIdx.x * 256 + threadIdx.x;
  float s = 0, q = 0;
  for (int b = 0; b < 64; ++b) {
    s += p2s[(size_t)b * NCOL1 + c];
    q += p2q[(size_t)b * NCOL1 + c];
  }
  float mean = s * (1.0f / B_N);
  float var = q * (1.0f / B_N) - mean * mean;
  float rstd = rsqrtf(var + EPS);
  float aa = rstd * g2[c];
  a2[c] = aa;
  c2[c] = b2[c] - mean * aa;
}

// ---------------- GEMM2 fused: out2 = sigmoid(G1*a2+c2) @ W2b^T ----------
__global__ __launch_bounds__(256) void k_gemm2(
    const __bf16* __restrict__ G1, const __bf16* __restrict__ W2b,
    const float* __restrict__ a2, const float* __restrict__ c2,
    float* __restrict__ out2) {
  const int tid = threadIdx.x;
  const int wave = tid >> 6, lane = tid & 63;
  const int m0 = blockIdx.x * 64;
  const int d = blockIdx.y;
  const int fr = lane & 15, fk = (lane >> 4) * 8;
  const __bf16* Arow = G1 + (size_t)(m0 + wave * 16 + fr) * NCOL1 + d * F_N;
  const __bf16* Wd = W2b + (size_t)d * O_N * F_N;
  const float* ap = a2 + d * F_N;
  const float* cp = c2 + d * F_N;
  f32x4 acc[2] = {};
  for (int k0 = 0; k0 < F_N; k0 += 32) {
    bf16x8 av = *(const bf16x8*)(Arow + k0 + fk);
    f32x4 aa0 = *(const f32x4*)(ap + k0 + fk);
    f32x4 aa1 = *(const f32x4*)(ap + k0 + fk + 4);
    f32x4 cc0 = *(const f32x4*)(cp + k0 + fk);
    f32x4 cc1 = *(const f32x4*)(cp + k0 + fk + 4);
    bf16x8 af;
#pragma unroll
    for (int j = 0; j < 4; ++j) {
      float v = (float)av[j] * aa0[j] + cc0[j];
      af[j] = (__bf16)(1.0f / (1.0f + __expf(-v)));
    }
#pragma unroll
    for (int j = 0; j < 4; ++j) {
      float v = (float)av[4 + j] * aa1[j] + cc1[j];
      af[4 + j] = (__bf16)(1.0f / (1.0f + __expf(-v)));
    }
    bf16x8 b0 = *(const bf16x8*)(Wd + (size_t)fr * F_N + k0 + fk);
    bf16x8 b1 = *(const bf16x8*)(Wd + (size_t)(16 + fr) * F_N + k0 + fk);
    acc[0] = __builtin_amdgcn_mfma_f32_16x16x32_bf16(af, b0, acc[0], 0, 0, 0);
    acc[1] = __builtin_amdgcn_mfma_f32_16x16x32_bf16(af, b1, acc[1], 0, 0, 0);
  }
  const int cr = (lane >> 4) * 4, cc = lane & 15;
#pragma unroll
  for (int n = 0; n < 2; ++n)
#pragma unroll
    for (int r = 0; r < 4; ++r)
      out2[(size_t)(m0 + wave * 16 + cr + r) * NCOL2 + d * O_N + n * 16 + cc] =
          acc[n][r];
}

// ---------------- BN3 stats on out2 ----------------
__global__ __launch_bounds__(128) void k_stats3_partial(
    const float* __restrict__ out2, float* __restrict__ part) {
  int t = threadIdx.x, blk = blockIdx.x;
  float s = 0, q = 0;
  int r0 = blk * 128;
  for (int r = r0; r < r0 + 128; ++r) {
    float v = out2[(size_t)r * NCOL2 + t];
    s += v;
    q += v * v;
  }
  part[(size_t)blk * 256 + t] = s;
  part[(size_t)blk * 256 + 128 + t] = q;
}

__global__ __launch_bounds__(128) void k_stats3_final(
    const float* __restrict__ part, const float* __restrict__ g3,
    const float* __restrict__ b3, float* __restrict__ a3,
    float* __restrict__ c3) {
  int c = threadIdx.x;
  float s = 0, q = 0;
  for (int b = 0; b < 128; ++b) {
    s += part[(size_t)b * 256 + c];
    q += part[(size_t)b * 256 + 128 + c];
  }
  float mean = s * (1.0f / B_N);
  float var = q * (1.0f / B_N) - mean * mean;
  float rstd = rsqrtf(var + EPS);
  float aa = rstd * g3[c];
  a3[c] = aa;
  c3[c] = b3[c] - mean * aa;
}

// ---------------- final: out = sigmoid(out2*a3+c3) ----------------
__global__ __launch_bounds__(256) void k_final(const float* __restrict__ out2,
                                               const float* __restrict__ a3,
                                               const float* __restrict__ c3,
                                               float* __restrict__ out) {
  size_t base = (size_t)(blockIdx.x * 256 + threadIdx.x) * 4;
  int c = (int)(base & (NCOL2 - 1));
  f32x4 v = *(const f32x4*)(out2 + base);
  f32x4 a = *(const f32x4*)(a3 + c);
  f32x4 cc = *(const f32x4*)(c3 + c);
  f32x4 o;
#pragma unroll
  for (int j = 0; j < 4; ++j)
    o[j] = 1.0f / (1.0f + __expf(-(v[j] * a[j] + cc[j])));
  *(f32x4*)(out + base) = o;
}

extern "C" void kernel_launch(void* const* d_in, const int* in_sizes, int n_in,
                              void* d_out, int out_size, void* d_ws,
                              size_t ws_size, hipStream_t stream) {
  (void)in_sizes; (void)n_in; (void)out_size; (void)ws_size;
  const float* x = (const float*)d_in[0];
  const float* W1 = (const float*)d_in[1];
  const float* W2 = (const float*)d_in[2];
  const float* g1 = (const float*)d_in[3];
  // d_in[4] = b1: per-column constant after GEMM1, annihilated by BN2 mean-sub.
  const float* g2 = (const float*)d_in[5];
  const float* b2 = (const float*)d_in[6];
  const float* g3 = (const float*)d_in[7];
  const float* b3 = (const float*)d_in[8];
  float* out = (float*)d_out;

  char* ws = (char*)d_ws;
  size_t off = 0;
  auto alloc = [&](size_t bytes) -> void* {
    void* p = ws + off;
    off = (off + bytes + 255) & ~(size_t)255;
    return p;
  };
  float* rstdx = (float*)alloc((size_t)F_N * 4);
  float* a2 = (float*)alloc((size_t)NCOL1 * 4);
  float* c2 = (float*)alloc((size_t)NCOL1 * 4);
  float* a3 = (float*)alloc((size_t)NCOL2 * 4);
  float* c3 = (float*)alloc((size_t)NCOL2 * 4);
  float* part1 = (float*)alloc((size_t)128 * 2048 * 4);
  float* p2s = (float*)alloc((size_t)64 * NCOL1 * 4);
  float* p2q = (float*)alloc((size_t)64 * NCOL1 * 4);
  float* part3 = (float*)alloc((size_t)128 * 256 * 4);
  __bf16* W1b = (__bf16*)alloc((size_t)D_N * F_N * F_N * 2);
  __bf16* W2b = (__bf16*)alloc((size_t)D_N * O_N * F_N * 2);
  __bf16* xb = (__bf16*)alloc((size_t)B_N * F_N * 2);
  __bf16* G1 = (__bf16*)alloc((size_t)B_N * NCOL1 * 2);
  float* out2 = (float*)alloc((size_t)B_N * NCOL2 * 4);

  k_stats_x_conv<<<128, 256, 0, stream>>>(x, part1, xb);
  k_stats_x_final<<<4, 256, 0, stream>>>(part1, rstdx);
  k_fold_w1<<<4096, 256, 0, stream>>>(W1, g1, rstdx, W1b);
  k_fold_w2<<<128, 256, 0, stream>>>(W2, W2b);
  k_gemm1<<<1024, 512, 0, stream>>>(xb, W1b, G1, p2s, p2q);
  k_stats2_final<<<16, 256, 0, stream>>>(p2s, p2q, g2, b2, a2, c2);
  k_gemm2<<<dim3(256, 4), 256, 0, stream>>>(G1, W2b, a2, c2, out2);
  k_stats3_partial<<<128, 128, 0, stream>>>(out2, part3);
  k_stats3_final<<<1, 128, 0, stream>>>(part3, g3, b3, a3, c3);
  k_final<<<2048, 256, 0, stream>>>(out2, a3, c3, out);
}

// Round 3
// 299.535 us; speedup vs baseline: 1.0989x; 1.0139x over previous
//
#include <hip/hip_runtime.h>
#include <hip/hip_bf16.h>
#include <stdint.h>

#define B_N 16384
#define F_N 1024
#define D_N 4
#define O_N 32
#define NCOL1 (D_N * F_N) /* 4096 */
#define NCOL2 (D_N * O_N) /* 128  */

static constexpr float EPS = 1e-5f;

typedef __bf16 bf16x8 __attribute__((ext_vector_type(8)));
typedef __bf16 bf16x4 __attribute__((ext_vector_type(4)));
typedef float  f32x4  __attribute__((ext_vector_type(4)));

// global -> LDS async copy, 16B per lane. LDS dest must be wave-uniform base.
#define GLD16(gp, lp)                                                          \
  __builtin_amdgcn_global_load_lds(                                            \
      (__attribute__((address_space(1))) void*)(uintptr_t)(gp),                \
      (__attribute__((address_space(3))) void*)(lp), 16, 0, 0)

// ---------------- BN1 stats on x + convert x->bf16 (fused, one pass) -------
// No mean subtraction / no rstd applied to x: rstd folds into W1, the mean
// shift is annihilated by BN2's mean subtraction.
__global__ __launch_bounds__(256) void k_stats_x_conv(
    const float* __restrict__ x, float* __restrict__ part,
    __bf16* __restrict__ xb) {
  int t = threadIdx.x, blk = blockIdx.x;
  const float4* xr = (const float4*)x;
  float s0 = 0, s1 = 0, s2 = 0, s3 = 0, q0 = 0, q1 = 0, q2 = 0, q3 = 0;
  int r0 = blk * 64;
  for (int r = r0; r < r0 + 64; ++r) {
    float4 v = xr[(size_t)r * (F_N / 4) + t];
    s0 += v.x; q0 += v.x * v.x;
    s1 += v.y; q1 += v.y * v.y;
    s2 += v.z; q2 += v.z * v.z;
    s3 += v.w; q3 += v.w * v.w;
    bf16x4 o;
    o[0] = (__bf16)v.x; o[1] = (__bf16)v.y; o[2] = (__bf16)v.z; o[3] = (__bf16)v.w;
    *(bf16x4*)(xb + (size_t)r * F_N + t * 4) = o;
  }
  float* p = part + (size_t)blk * 2048;
  p[t * 4 + 0] = s0; p[t * 4 + 1] = s1; p[t * 4 + 2] = s2; p[t * 4 + 3] = s3;
  p[1024 + t * 4 + 0] = q0; p[1024 + t * 4 + 1] = q1;
  p[1024 + t * 4 + 2] = q2; p[1024 + t * 4 + 3] = q3;
}

__global__ __launch_bounds__(256) void k_stats_x_final(
    const float* __restrict__ part, float* __restrict__ rstdx) {
  int c = blockIdx.x * 256 + threadIdx.x;
  float s = 0, q = 0;
  for (int b = 0; b < 256; ++b) {
    s += part[(size_t)b * 2048 + c];
    q += part[(size_t)b * 2048 + 1024 + c];
  }
  float mean = s * (1.0f / B_N);
  float var = q * (1.0f / B_N) - mean * mean;
  rstdx[c] = rsqrtf(var + EPS);
}

// ---------------- fold g1 * rstd1 into W1, convert to bf16 ----------------
__global__ __launch_bounds__(256) void k_fold_w1(const float* __restrict__ W1,
                                                 const float* __restrict__ g1,
                                                 const float* __restrict__ rstdx,
                                                 __bf16* __restrict__ W1b) {
  size_t base = (size_t)(blockIdx.x * 256 + threadIdx.x) * 4;
  int f = (int)(base & (F_N - 1));
  int d = (int)(base >> 20);
  float4 w = *(const float4*)(W1 + base);
  float4 g = *(const float4*)(g1 + d * F_N + f);
  float4 r = *(const float4*)(rstdx + f);
  bf16x4 o;
  o[0] = (__bf16)(w.x * g.x * r.x); o[1] = (__bf16)(w.y * g.y * r.y);
  o[2] = (__bf16)(w.z * g.z * r.z); o[3] = (__bf16)(w.w * g.w * r.w);
  *(bf16x4*)(W1b + base) = o;
}

__global__ __launch_bounds__(256) void k_fold_w2(const float* __restrict__ W2,
                                                 __bf16* __restrict__ W2b) {
  size_t base = (size_t)(blockIdx.x * 256 + threadIdx.x) * 4;
  float4 w = *(const float4*)(W2 + base);
  bf16x4 o;
  o[0] = (__bf16)w.x; o[1] = (__bf16)w.y; o[2] = (__bf16)w.z; o[3] = (__bf16)w.w;
  *(bf16x4*)(W2b + base) = o;
}

// ---------------- GEMM1: G1[16384][4096] = xb @ W1b^T, 256^2 8-phase -------
// BM=BN=256, BK=64 (two K-halves of 32), 8 waves (2M x 4N), 128 KiB LDS.
// K-half LDS layout [256 rows][4 x 16B slots]; storage map swizzles the slot
// by (row>>1)&3 (rule #21: applied on BOTH the pre-swizzled global source
// and the ds_read address). Post-swizzle each 16-lane quarter covers all 8
// 4-bank groups with 2 lanes each (2-way = free, m136).
// Counted vmcnt(4) at phases 2/4 of each K-tile; never drained in the loop.
// Epilogue: C write (bf16) + per-block BN2 column partial sums.
__global__ __launch_bounds__(512, 2) void k_gemm1(
    const __bf16* __restrict__ A, const __bf16* __restrict__ Bw,
    __bf16* __restrict__ C, float* __restrict__ p2s, float* __restrict__ p2q) {
  __shared__ __bf16 ldsA[2][2][256 * 32];
  __shared__ __bf16 ldsB[2][2][256 * 32];
  const int tid = threadIdx.x;
  const int wave = tid >> 6, lane = tid & 63;
  const int wm = wave >> 2, wn = wave & 3;
  // XCD-aware remap: XCD c owns bm strip [c*8, c*8+8) x all 16 bn.
  int bid = (int)blockIdx.x;
  const int c_ = bid & 7, q_ = bid >> 3;
  const int bm = c_ * 8 + (q_ >> 4), bn = q_ & 15;
  const int m0 = bm * 256, n0 = bn * 256;
  const int fr = lane & 15, kg = lane >> 4;
  // swizzled ds_read slot (16B units): kg ^ ((row>>1)&3); all row-base terms
  // in the frag reads are multiples of 64 so (row>>1)&3 == (fr>>1)&3.
  const int swz8 = (kg ^ ((fr >> 1) & 3)) * 8; // element offset
  // staging source addressing: 512 thr x 16B = 8KB per call (128 rows x 64B).
  // thread -> LDS (row=tid>>2, slot=tid&3); source supplies logical slot
  // (tid&3) ^ ((srow>>1)&3) = (tid&3) ^ ((tid>>3)&3).
  const int srow = tid >> 2;
  const int scb = ((tid & 3) ^ ((tid >> 3) & 3)) * 16;
  const char* Ab = (const char*)A + (size_t)(m0 + srow) * (F_N * 2) + scb;
  const char* Bb = (const char*)Bw + (size_t)(n0 + srow) * (F_N * 2) + scb;
  char* ldsAx = (char*)&ldsA[0][0][0];
  char* ldsBx = (char*)&ldsB[0][0][0];
  const int wo = wave * 1024;

#define SA(buf_, kk_, kb_)                                                     \
  do {                                                                         \
    GLD16(Ab + (kb_) + (kk_) * 64,                                             \
          ldsAx + (buf_) * 32768 + (kk_) * 16384 + wo);                        \
    GLD16(Ab + 128 * (F_N * 2) + (kb_) + (kk_) * 64,                           \
          ldsAx + (buf_) * 32768 + (kk_) * 16384 + 8192 + wo);                 \
  } while (0)
#define SBv(buf_, kk_, kb_)                                                    \
  do {                                                                         \
    GLD16(Bb + (kb_) + (kk_) * 64,                                             \
          ldsBx + (buf_) * 32768 + (kk_) * 16384 + wo);                        \
    GLD16(Bb + 128 * (F_N * 2) + (kb_) + (kk_) * 64,                           \
          ldsBx + (buf_) * 32768 + (kk_) * 16384 + 8192 + wo);                 \
  } while (0)
#define LDA4(buf_, kk_, qm_)                                                   \
  { _Pragma("unroll") for (int i_ = 0; i_ < 4; ++i_)                           \
      afr[i_] = *(const bf16x8*)&ldsA[buf_][kk_]                               \
          [(wm * 128 + (qm_) * 64 + i_ * 16 + fr) * 32 + swz8]; }
#define LDB4(buf_, kk_)                                                        \
  { _Pragma("unroll") for (int i_ = 0; i_ < 4; ++i_)                           \
      bfr[i_] = *(const bf16x8*)&ldsB[buf_][kk_]                               \
          [(wn * 64 + i_ * 16 + fr) * 32 + swz8]; }
#define MFMA16(qm_)                                                            \
  { _Pragma("unroll") for (int i_ = 0; i_ < 4; ++i_)                           \
      _Pragma("unroll") for (int j_ = 0; j_ < 4; ++j_)                         \
        acc[(qm_) * 4 + i_][j_] = __builtin_amdgcn_mfma_f32_16x16x32_bf16(     \
            afr[i_], bfr[j_], acc[(qm_) * 4 + i_][j_], 0, 0, 0); }
#define BAR() __builtin_amdgcn_s_barrier()
#define WAITLGKM()                                                             \
  do {                                                                         \
    asm volatile("s_waitcnt lgkmcnt(0)" ::: "memory");                         \
    __builtin_amdgcn_sched_barrier(0);                                         \
  } while (0)
#define WAITVM4() asm volatile("s_waitcnt vmcnt(4)" ::: "memory")
#define PRIO1() __builtin_amdgcn_s_setprio(1)
#define PRIO0() __builtin_amdgcn_s_setprio(0)

  f32x4 acc[8][4] = {};
  bf16x8 afr[4], bfr[4];

  // prologue: tile 0 halves in stream order B-K0, A-K0, B-K1, A-K1
  SBv(0, 0, 0); SA(0, 0, 0); SBv(0, 1, 0); SA(0, 1, 0);
  asm volatile("s_waitcnt vmcnt(4)" ::: "memory");
  BAR();

  // 16 K-tiles, 2 per iteration (8 phases). Tile t reads buf t&1; phases
  // stage tile t+1's halves into buf (t+1)&1 in order BK0,AK0,BK1,AK1.
  for (int t = 0; t < 16; t += 2) {
    const int kn1 = (t + 1) * 128;                     // byte offset of K-tile t+1
    const int kn2 = (t + 2 < 16) ? (t + 2) * 128 : 0;  // dummy clamp on tail
    // tile t (buf 0)
    LDA4(0, 0, 0); LDB4(0, 0); SBv(1, 0, kn1); BAR(); WAITLGKM(); PRIO1(); MFMA16(0); PRIO0(); BAR();
    LDA4(0, 0, 1);             SA (1, 0, kn1); BAR(); WAITLGKM(); PRIO1(); MFMA16(1); PRIO0(); WAITVM4(); BAR();
    LDA4(0, 1, 0); LDB4(0, 1); SBv(1, 1, kn1); BAR(); WAITLGKM(); PRIO1(); MFMA16(0); PRIO0(); BAR();
    LDA4(0, 1, 1);             SA (1, 1, kn1); BAR(); WAITLGKM(); PRIO1(); MFMA16(1); PRIO0(); WAITVM4(); BAR();
    // tile t+1 (buf 1)
    LDA4(1, 0, 0); LDB4(1, 0); SBv(0, 0, kn2); BAR(); WAITLGKM(); PRIO1(); MFMA16(0); PRIO0(); BAR();
    LDA4(1, 0, 1);             SA (0, 0, kn2); BAR(); WAITLGKM(); PRIO1(); MFMA16(1); PRIO0(); WAITVM4(); BAR();
    LDA4(1, 1, 0); LDB4(1, 1); SBv(0, 1, kn2); BAR(); WAITLGKM(); PRIO1(); MFMA16(0); PRIO0(); BAR();
    LDA4(1, 1, 1);             SA (0, 1, kn2); BAR(); WAITLGKM(); PRIO1(); MFMA16(1); PRIO0(); WAITVM4(); BAR();
  }

  // ---- epilogue: C write ----
  const int cr = kg * 4, cc = fr;
#pragma unroll
  for (int mi = 0; mi < 8; ++mi)
#pragma unroll
    for (int ni = 0; ni < 4; ++ni) {
      int row = m0 + wm * 128 + mi * 16 + cr;
      int col = n0 + wn * 64 + ni * 16 + cc;
#pragma unroll
      for (int r = 0; r < 4; ++r)
        C[(size_t)(row + r) * NCOL1 + col] = (__bf16)acc[mi][ni][r];
    }

  // ---- epilogue: BN2 per-block column partial sums (from f32 acc) ----
  // Overlay small reduce buffer on ldsA[1][0] (not touched by in-flight
  // tail dummy stages, which target buf 0 only; last reads were tile 15 ph2).
  float* srs = (float*)&ldsA[1][0][0];
  float* srq = srs + 512;
  __syncthreads();
#pragma unroll
  for (int ni = 0; ni < 4; ++ni) {
    float ss = 0, qq = 0;
#pragma unroll
    for (int mi = 0; mi < 8; ++mi) {
      f32x4 v = acc[mi][ni];
#pragma unroll
      for (int r = 0; r < 4; ++r) { ss += v[r]; qq += v[r] * v[r]; }
    }
    ss += __shfl_xor(ss, 16); ss += __shfl_xor(ss, 32);
    qq += __shfl_xor(qq, 16); qq += __shfl_xor(qq, 32);
    if (lane < 16) {
      srs[wave * 64 + ni * 16 + lane] = ss;
      srq[wave * 64 + ni * 16 + lane] = qq;
    }
  }
  __syncthreads();
  if (tid < 256) {
    int j = tid, wnn = j >> 6, jj = j & 63;
    float S = srs[wnn * 64 + jj] + srs[(4 + wnn) * 64 + jj];
    float Q = srq[wnn * 64 + jj] + srq[(4 + wnn) * 64 + jj];
    p2s[(size_t)bm * NCOL1 + n0 + j] = S;
    p2q[(size_t)bm * NCOL1 + n0 + j] = Q;
  }
#undef SA
#undef SBv
#undef LDA4
#undef LDB4
#undef MFMA16
#undef BAR
#undef WAITLGKM
#undef WAITVM4
#undef PRIO1
#undef PRIO0
}

// ---------------- BN2 finalize from per-block partials ----------------
__global__ __launch_bounds__(256) void k_stats2_final(
    const float* __restrict__ p2s, const float* __restrict__ p2q,
    const float* __restrict__ g2, const float* __restrict__ b2,
    float* __restrict__ a2, float* __restrict__ c2) {
  int c = blockIdx.x * 256 + threadIdx.x;
  float s = 0, q = 0;
  for (int b = 0; b < 64; ++b) {
    s += p2s[(size_t)b * NCOL1 + c];
    q += p2q[(size_t)b * NCOL1 + c];
  }
  float mean = s * (1.0f / B_N);
  float var = q * (1.0f / B_N) - mean * mean;
  float rstd = rsqrtf(var + EPS);
  float aa = rstd * g2[c];
  a2[c] = aa;
  c2[c] = b2[c] - mean * aa;
}

// ---------------- GEMM2 fused: out2 = sigmoid(G1*a2+c2) @ W2b^T ----------
__global__ __launch_bounds__(256) void k_gemm2(
    const __bf16* __restrict__ G1, const __bf16* __restrict__ W2b,
    const float* __restrict__ a2, const float* __restrict__ c2,
    float* __restrict__ out2) {
  const int tid = threadIdx.x;
  const int wave = tid >> 6, lane = tid & 63;
  const int m0 = blockIdx.x * 64;
  const int d = blockIdx.y;
  const int fr = lane & 15, fk = (lane >> 4) * 8;
  const __bf16* Arow = G1 + (size_t)(m0 + wave * 16 + fr) * NCOL1 + d * F_N;
  const __bf16* Wd = W2b + (size_t)d * O_N * F_N;
  const float* ap = a2 + d * F_N;
  const float* cp = c2 + d * F_N;
  f32x4 acc[2] = {};
  for (int k0 = 0; k0 < F_N; k0 += 32) {
    bf16x8 av = *(const bf16x8*)(Arow + k0 + fk);
    f32x4 aa0 = *(const f32x4*)(ap + k0 + fk);
    f32x4 aa1 = *(const f32x4*)(ap + k0 + fk + 4);
    f32x4 cc0 = *(const f32x4*)(cp + k0 + fk);
    f32x4 cc1 = *(const f32x4*)(cp + k0 + fk + 4);
    bf16x8 af;
#pragma unroll
    for (int j = 0; j < 4; ++j) {
      float v = (float)av[j] * aa0[j] + cc0[j];
      af[j] = (__bf16)(1.0f / (1.0f + __expf(-v)));
    }
#pragma unroll
    for (int j = 0; j < 4; ++j) {
      float v = (float)av[4 + j] * aa1[j] + cc1[j];
      af[4 + j] = (__bf16)(1.0f / (1.0f + __expf(-v)));
    }
    bf16x8 b0 = *(const bf16x8*)(Wd + (size_t)fr * F_N + k0 + fk);
    bf16x8 b1 = *(const bf16x8*)(Wd + (size_t)(16 + fr) * F_N + k0 + fk);
    acc[0] = __builtin_amdgcn_mfma_f32_16x16x32_bf16(af, b0, acc[0], 0, 0, 0);
    acc[1] = __builtin_amdgcn_mfma_f32_16x16x32_bf16(af, b1, acc[1], 0, 0, 0);
  }
  const int cr = (lane >> 4) * 4, cc = lane & 15;
#pragma unroll
  for (int n = 0; n < 2; ++n)
#pragma unroll
    for (int r = 0; r < 4; ++r)
      out2[(size_t)(m0 + wave * 16 + cr + r) * NCOL2 + d * O_N + n * 16 + cc] =
          acc[n][r];
}

// ---------------- BN3 stats on out2 ----------------
__global__ __launch_bounds__(128) void k_stats3_partial(
    const float* __restrict__ out2, float* __restrict__ part) {
  int t = threadIdx.x, blk = blockIdx.x;
  float s = 0, q = 0;
  int r0 = blk * 128;
  for (int r = r0; r < r0 + 128; ++r) {
    float v = out2[(size_t)r * NCOL2 + t];
    s += v;
    q += v * v;
  }
  part[(size_t)blk * 256 + t] = s;
  part[(size_t)blk * 256 + 128 + t] = q;
}

__global__ __launch_bounds__(128) void k_stats3_final(
    const float* __restrict__ part, const float* __restrict__ g3,
    const float* __restrict__ b3, float* __restrict__ a3,
    float* __restrict__ c3) {
  int c = threadIdx.x;
  float s = 0, q = 0;
  for (int b = 0; b < 128; ++b) {
    s += part[(size_t)b * 256 + c];
    q += part[(size_t)b * 256 + 128 + c];
  }
  float mean = s * (1.0f / B_N);
  float var = q * (1.0f / B_N) - mean * mean;
  float rstd = rsqrtf(var + EPS);
  float aa = rstd * g3[c];
  a3[c] = aa;
  c3[c] = b3[c] - mean * aa;
}

// ---------------- final: out = sigmoid(out2*a3+c3) ----------------
__global__ __launch_bounds__(256) void k_final(const float* __restrict__ out2,
                                               const float* __restrict__ a3,
                                               const float* __restrict__ c3,
                                               float* __restrict__ out) {
  size_t base = (size_t)(blockIdx.x * 256 + threadIdx.x) * 4;
  int c = (int)(base & (NCOL2 - 1));
  f32x4 v = *(const f32x4*)(out2 + base);
  f32x4 a = *(const f32x4*)(a3 + c);
  f32x4 cc = *(const f32x4*)(c3 + c);
  f32x4 o;
#pragma unroll
  for (int j = 0; j < 4; ++j)
    o[j] = 1.0f / (1.0f + __expf(-(v[j] * a[j] + cc[j])));
  *(f32x4*)(out + base) = o;
}

extern "C" void kernel_launch(void* const* d_in, const int* in_sizes, int n_in,
                              void* d_out, int out_size, void* d_ws,
                              size_t ws_size, hipStream_t stream) {
  (void)in_sizes; (void)n_in; (void)out_size; (void)ws_size;
  const float* x = (const float*)d_in[0];
  const float* W1 = (const float*)d_in[1];
  const float* W2 = (const float*)d_in[2];
  const float* g1 = (const float*)d_in[3];
  // d_in[4] = b1: per-column constant after GEMM1, annihilated by BN2 mean-sub.
  const float* g2 = (const float*)d_in[5];
  const float* b2 = (const float*)d_in[6];
  const float* g3 = (const float*)d_in[7];
  const float* b3 = (const float*)d_in[8];
  float* out = (float*)d_out;

  char* ws = (char*)d_ws;
  size_t off = 0;
  auto alloc = [&](size_t bytes) -> void* {
    void* p = ws + off;
    off = (off + bytes + 255) & ~(size_t)255;
    return p;
  };
  float* rstdx = (float*)alloc((size_t)F_N * 4);
  float* a2 = (float*)alloc((size_t)NCOL1 * 4);
  float* c2 = (float*)alloc((size_t)NCOL1 * 4);
  float* a3 = (float*)alloc((size_t)NCOL2 * 4);
  float* c3 = (float*)alloc((size_t)NCOL2 * 4);
  float* part1 = (float*)alloc((size_t)256 * 2048 * 4);
  float* p2s = (float*)alloc((size_t)64 * NCOL1 * 4);
  float* p2q = (float*)alloc((size_t)64 * NCOL1 * 4);
  float* part3 = (float*)alloc((size_t)128 * 256 * 4);
  __bf16* W1b = (__bf16*)alloc((size_t)D_N * F_N * F_N * 2);
  __bf16* W2b = (__bf16*)alloc((size_t)D_N * O_N * F_N * 2);
  __bf16* xb = (__bf16*)alloc((size_t)B_N * F_N * 2);
  __bf16* G1 = (__bf16*)alloc((size_t)B_N * NCOL1 * 2);
  float* out2 = (float*)alloc((size_t)B_N * NCOL2 * 4);

  k_stats_x_conv<<<256, 256, 0, stream>>>(x, part1, xb);
  k_stats_x_final<<<4, 256, 0, stream>>>(part1, rstdx);
  k_fold_w1<<<4096, 256, 0, stream>>>(W1, g1, rstdx, W1b);
  k_fold_w2<<<128, 256, 0, stream>>>(W2, W2b);
  k_gemm1<<<1024, 512, 0, stream>>>(xb, W1b, G1, p2s, p2q);
  k_stats2_final<<<16, 256, 0, stream>>>(p2s, p2q, g2, b2, a2, c2);
  k_gemm2<<<dim3(256, 4), 256, 0, stream>>>(G1, W2b, a2, c2, out2);
  k_stats3_partial<<<128, 128, 0, stream>>>(out2, part3);
  k_stats3_final<<<1, 128, 0, stream>>>(part3, g3, b3, a3, c3);
  k_final<<<2048, 256, 0, stream>>>(out2, a3, c3, out);
}

// Round 4
// 267.301 us; speedup vs baseline: 1.2314x; 1.1206x over previous
//
#include <hip/hip_runtime.h>
#include <hip/hip_bf16.h>
#include <stdint.h>

#define B_N 16384
#define F_N 1024
#define D_N 4
#define O_N 32
#define NCOL1 (D_N * F_N) /* 4096 */
#define NCOL2 (D_N * O_N) /* 128  */

static constexpr float EPS = 1e-5f;

typedef __bf16 bf16x8 __attribute__((ext_vector_type(8)));
typedef __bf16 bf16x4 __attribute__((ext_vector_type(4)));
typedef float  f32x4  __attribute__((ext_vector_type(4)));

// global -> LDS async copy, 16B per lane. LDS dest must be wave-uniform base.
#define GLD16(gp, lp)                                                          \
  __builtin_amdgcn_global_load_lds(                                            \
      (__attribute__((address_space(1))) void*)(uintptr_t)(gp),                \
      (__attribute__((address_space(3))) void*)(lp), 16, 0, 0)

// ---------------- BN1 stats on x + convert x->bf16 (fused, one pass) -------
__global__ __launch_bounds__(256) void k_stats_x_conv(
    const float* __restrict__ x, float* __restrict__ part,
    __bf16* __restrict__ xb) {
  int t = threadIdx.x, blk = blockIdx.x;
  const float4* xr = (const float4*)x;
  float s0 = 0, s1 = 0, s2 = 0, s3 = 0, q0 = 0, q1 = 0, q2 = 0, q3 = 0;
  int r0 = blk * 64;
  for (int r = r0; r < r0 + 64; ++r) {
    float4 v = xr[(size_t)r * (F_N / 4) + t];
    s0 += v.x; q0 += v.x * v.x;
    s1 += v.y; q1 += v.y * v.y;
    s2 += v.z; q2 += v.z * v.z;
    s3 += v.w; q3 += v.w * v.w;
    bf16x4 o;
    o[0] = (__bf16)v.x; o[1] = (__bf16)v.y; o[2] = (__bf16)v.z; o[3] = (__bf16)v.w;
    *(bf16x4*)(xb + (size_t)r * F_N + t * 4) = o;
  }
  float* p = part + (size_t)blk * 2048;
  p[t * 4 + 0] = s0; p[t * 4 + 1] = s1; p[t * 4 + 2] = s2; p[t * 4 + 3] = s3;
  p[1024 + t * 4 + 0] = q0; p[1024 + t * 4 + 1] = q1;
  p[1024 + t * 4 + 2] = q2; p[1024 + t * 4 + 3] = q3;
}

__global__ __launch_bounds__(256) void k_stats_x_final(
    const float* __restrict__ part, float* __restrict__ rstdx) {
  int c = blockIdx.x * 256 + threadIdx.x;
  float s = 0, q = 0;
  for (int b = 0; b < 256; ++b) {
    s += part[(size_t)b * 2048 + c];
    q += part[(size_t)b * 2048 + 1024 + c];
  }
  float mean = s * (1.0f / B_N);
  float var = q * (1.0f / B_N) - mean * mean;
  rstdx[c] = rsqrtf(var + EPS);
}

// ---------------- fold g1 * rstd1 into W1, convert to bf16 ----------------
__global__ __launch_bounds__(256) void k_fold_w1(const float* __restrict__ W1,
                                                 const float* __restrict__ g1,
                                                 const float* __restrict__ rstdx,
                                                 __bf16* __restrict__ W1b) {
  size_t base = (size_t)(blockIdx.x * 256 + threadIdx.x) * 4;
  int f = (int)(base & (F_N - 1));
  int d = (int)(base >> 20);
  float4 w = *(const float4*)(W1 + base);
  float4 g = *(const float4*)(g1 + d * F_N + f);
  float4 r = *(const float4*)(rstdx + f);
  bf16x4 o;
  o[0] = (__bf16)(w.x * g.x * r.x); o[1] = (__bf16)(w.y * g.y * r.y);
  o[2] = (__bf16)(w.z * g.z * r.z); o[3] = (__bf16)(w.w * g.w * r.w);
  *(bf16x4*)(W1b + base) = o;
}

__global__ __launch_bounds__(256) void k_fold_w2(const float* __restrict__ W2,
                                                 __bf16* __restrict__ W2b) {
  size_t base = (size_t)(blockIdx.x * 256 + threadIdx.x) * 4;
  float4 w = *(const float4*)(W2 + base);
  bf16x4 o;
  o[0] = (__bf16)w.x; o[1] = (__bf16)w.y; o[2] = (__bf16)w.z; o[3] = (__bf16)w.w;
  *(bf16x4*)(W2b + base) = o;
}

// ---------------- GEMM1: G1[16384][4096] = xb @ W1b^T, 256^2 pipelined -----
// BM=BN=256, BK=64 (two K-halves of 32), 8 waves (2M x 4N), 128 KiB LDS.
// Swizzled LDS slots (rule #21, both sides), XCD remap, and a 1-phase
// register pipeline: each phase pre-reads the NEXT phase's fragments into
// the alternate E/O register set, so the LDS port runs concurrently with
// the MFMA pipe. One barrier per phase; counted vmcnt(4) at phases 2 & 4.
__global__ __launch_bounds__(512, 2) void k_gemm1(
    const __bf16* __restrict__ A, const __bf16* __restrict__ Bw,
    __bf16* __restrict__ C, float* __restrict__ p2s, float* __restrict__ p2q) {
  __shared__ __bf16 ldsA[2][2][256 * 32];
  __shared__ __bf16 ldsB[2][2][256 * 32];
  const int tid = threadIdx.x;
  const int wave = tid >> 6, lane = tid & 63;
  const int wm = wave >> 2, wn = wave & 3;
  // XCD-aware remap: XCD c owns bm strip [c*8, c*8+8) x all 16 bn.
  int bid = (int)blockIdx.x;
  const int c_ = bid & 7, q_ = bid >> 3;
  const int bm = c_ * 8 + (q_ >> 4), bn = q_ & 15;
  const int m0 = bm * 256, n0 = bn * 256;
  const int fr = lane & 15, kg = lane >> 4;
  // swizzled ds_read slot: kg ^ ((fr>>1)&3) (row-base terms are mult of 64)
  const int swz8 = (kg ^ ((fr >> 1) & 3)) * 8;
  // staging: 512 thr x 16B; LDS (row=tid>>2, slot=tid&3); source supplies
  // logical slot (tid&3)^((tid>>3)&3).
  const int srow = tid >> 2;
  const int scb = ((tid & 3) ^ ((tid >> 3) & 3)) * 16;
  const char* Ab = (const char*)A + (size_t)(m0 + srow) * (F_N * 2) + scb;
  const char* Bb = (const char*)Bw + (size_t)(n0 + srow) * (F_N * 2) + scb;
  char* ldsAx = (char*)&ldsA[0][0][0];
  char* ldsBx = (char*)&ldsB[0][0][0];
  const int wo = wave * 1024;

#define SA(buf_, kk_, kb_)                                                     \
  do {                                                                         \
    GLD16(Ab + (kb_) + (kk_) * 64,                                             \
          ldsAx + (buf_) * 32768 + (kk_) * 16384 + wo);                        \
    GLD16(Ab + 128 * (F_N * 2) + (kb_) + (kk_) * 64,                           \
          ldsAx + (buf_) * 32768 + (kk_) * 16384 + 8192 + wo);                 \
  } while (0)
#define SBv(buf_, kk_, kb_)                                                    \
  do {                                                                         \
    GLD16(Bb + (kb_) + (kk_) * 64,                                             \
          ldsBx + (buf_) * 32768 + (kk_) * 16384 + wo);                        \
    GLD16(Bb + 128 * (F_N * 2) + (kb_) + (kk_) * 64,                           \
          ldsBx + (buf_) * 32768 + (kk_) * 16384 + 8192 + wo);                 \
  } while (0)
#define LDA4(dst_, buf_, kk_, qm_)                                             \
  { _Pragma("unroll") for (int i_ = 0; i_ < 4; ++i_)                           \
      dst_[i_] = *(const bf16x8*)&ldsA[buf_][kk_]                              \
          [(wm * 128 + (qm_) * 64 + i_ * 16 + fr) * 32 + swz8]; }
#define LDB4(dst_, buf_, kk_)                                                  \
  { _Pragma("unroll") for (int i_ = 0; i_ < 4; ++i_)                           \
      dst_[i_] = *(const bf16x8*)&ldsB[buf_][kk_]                              \
          [(wn * 64 + i_ * 16 + fr) * 32 + swz8]; }
#define MFMA16(a_, b_, qm_)                                                    \
  { _Pragma("unroll") for (int i_ = 0; i_ < 4; ++i_)                           \
      _Pragma("unroll") for (int j_ = 0; j_ < 4; ++j_)                         \
        acc[(qm_) * 4 + i_][j_] = __builtin_amdgcn_mfma_f32_16x16x32_bf16(     \
            a_[i_], b_[j_], acc[(qm_) * 4 + i_][j_], 0, 0, 0); }
#define BAR() __builtin_amdgcn_s_barrier()
#define SB0() __builtin_amdgcn_sched_barrier(0)
#define WAITVM4() asm volatile("s_waitcnt vmcnt(4)" ::: "memory")
#define PRIO1() __builtin_amdgcn_s_setprio(1)
#define PRIO0() __builtin_amdgcn_s_setprio(0)

  f32x4 acc[8][4] = {};
  bf16x8 afrE[4], afrO[4], bfrE[4], bfrO[4];

  // prologue: stage tile 0 (B-K0, A-K0, B-K1, A-K1); wait K0 halves; pre-read
  // the first phase's fragments.
  SBv(0, 0, 0); SA(0, 0, 0); SBv(0, 1, 0); SA(0, 1, 0);
  asm volatile("s_waitcnt vmcnt(4)" ::: "memory");
  BAR(); SB0();
  LDA4(afrE, 0, 0, 0); LDB4(bfrE, 0, 0);

  // Per tile t (buf b, staging tile t+1 into nb):
  //  ph1: stage B(nb,k0); BAR; pre-read A(b,k0,qm1)->O;        MFMA(E,BE,qm0)
  //  ph2: stage A(nb,k0); vmcnt4; BAR; pre-read A(b,k1,qm0)->E,
  //       B(b,k1)->BO;                                          MFMA(O,BE,qm1)
  //  ph3: stage B(nb,k1); BAR; pre-read A(b,k1,qm1)->O;        MFMA(E,BO,qm0)
  //  ph4: stage A(nb,k1); vmcnt4; BAR; pre-read A(nb,k0,qm0)->E,
  //       B(nb,k0)->BE;                                         MFMA(O,BO,qm1)
#define TILE(b_, nb_, kn_)                                                     \
  SBv(nb_, 0, kn_); BAR(); SB0();                                              \
  LDA4(afrO, b_, 0, 1);                                                        \
  PRIO1(); MFMA16(afrE, bfrE, 0); PRIO0();                                     \
  SA(nb_, 0, kn_); WAITVM4(); BAR(); SB0();                                    \
  LDA4(afrE, b_, 1, 0); LDB4(bfrO, b_, 1);                                     \
  PRIO1(); MFMA16(afrO, bfrE, 1); PRIO0();                                     \
  SBv(nb_, 1, kn_); BAR(); SB0();                                              \
  LDA4(afrO, b_, 1, 1);                                                        \
  PRIO1(); MFMA16(afrE, bfrO, 0); PRIO0();                                     \
  SA(nb_, 1, kn_); WAITVM4(); BAR(); SB0();                                    \
  LDA4(afrE, nb_, 0, 0); LDB4(bfrE, nb_, 0);                                   \
  PRIO1(); MFMA16(afrO, bfrO, 1); PRIO0();

  for (int t = 0; t < 16; t += 2) {
    const int kn1 = (t + 1) * 128;
    const int kn2 = (t + 2 < 16) ? (t + 2) * 128 : 0;  // tail wraps (harmless)
    TILE(0, 1, kn1)
    TILE(1, 0, kn2)
  }

  // ---- epilogue: C write ----
  const int cr = kg * 4, cc = fr;
#pragma unroll
  for (int mi = 0; mi < 8; ++mi)
#pragma unroll
    for (int ni = 0; ni < 4; ++ni) {
      int row = m0 + wm * 128 + mi * 16 + cr;
      int col = n0 + wn * 64 + ni * 16 + cc;
#pragma unroll
      for (int r = 0; r < 4; ++r)
        C[(size_t)(row + r) * NCOL1 + col] = (__bf16)acc[mi][ni][r];
    }

  // ---- epilogue: BN2 per-block column partial sums (from f32 acc) ----
  // Overlay on ldsA[1][*]: tail dummy stages target buf 0 only.
  float* srs = (float*)&ldsA[1][0][0];
  float* srq = srs + 512;
  __syncthreads();
#pragma unroll
  for (int ni = 0; ni < 4; ++ni) {
    float ss = 0, qq = 0;
#pragma unroll
    for (int mi = 0; mi < 8; ++mi) {
      f32x4 v = acc[mi][ni];
#pragma unroll
      for (int r = 0; r < 4; ++r) { ss += v[r]; qq += v[r] * v[r]; }
    }
    ss += __shfl_xor(ss, 16); ss += __shfl_xor(ss, 32);
    qq += __shfl_xor(qq, 16); qq += __shfl_xor(qq, 32);
    if (lane < 16) {
      srs[wave * 64 + ni * 16 + lane] = ss;
      srq[wave * 64 + ni * 16 + lane] = qq;
    }
  }
  __syncthreads();
  if (tid < 256) {
    int j = tid, wnn = j >> 6, jj = j & 63;
    float S = srs[wnn * 64 + jj] + srs[(4 + wnn) * 64 + jj];
    float Q = srq[wnn * 64 + jj] + srq[(4 + wnn) * 64 + jj];
    p2s[(size_t)bm * NCOL1 + n0 + j] = S;
    p2q[(size_t)bm * NCOL1 + n0 + j] = Q;
  }
#undef SA
#undef SBv
#undef LDA4
#undef LDB4
#undef MFMA16
#undef TILE
#undef BAR
#undef SB0
#undef WAITVM4
#undef PRIO1
#undef PRIO0
}

// ---------------- BN2 finalize from per-block partials ----------------
__global__ __launch_bounds__(256) void k_stats2_final(
    const float* __restrict__ p2s, const float* __restrict__ p2q,
    const float* __restrict__ g2, const float* __restrict__ b2,
    float* __restrict__ a2, float* __restrict__ c2) {
  int c = blockIdx.x * 256 + threadIdx.x;
  float s = 0, q = 0;
  for (int b = 0; b < 64; ++b) {
    s += p2s[(size_t)b * NCOL1 + c];
    q += p2q[(size_t)b * NCOL1 + c];
  }
  float mean = s * (1.0f / B_N);
  float var = q * (1.0f / B_N) - mean * mean;
  float rstd = rsqrtf(var + EPS);
  float aa = rstd * g2[c];
  a2[c] = aa;
  c2[c] = b2[c] - mean * aa;
}

// ---------------- GEMM2 fused: out2 = sigmoid(G1*a2+c2) @ W2b^T ----------
__global__ __launch_bounds__(256) void k_gemm2(
    const __bf16* __restrict__ G1, const __bf16* __restrict__ W2b,
    const float* __restrict__ a2, const float* __restrict__ c2,
    float* __restrict__ out2) {
  const int tid = threadIdx.x;
  const int wave = tid >> 6, lane = tid & 63;
  const int m0 = blockIdx.x * 64;
  const int d = blockIdx.y;
  const int fr = lane & 15, fk = (lane >> 4) * 8;
  const __bf16* Arow = G1 + (size_t)(m0 + wave * 16 + fr) * NCOL1 + d * F_N;
  const __bf16* Wd = W2b + (size_t)d * O_N * F_N;
  const float* ap = a2 + d * F_N;
  const float* cp = c2 + d * F_N;
  f32x4 acc[2] = {};
  for (int k0 = 0; k0 < F_N; k0 += 32) {
    bf16x8 av = *(const bf16x8*)(Arow + k0 + fk);
    f32x4 aa0 = *(const f32x4*)(ap + k0 + fk);
    f32x4 aa1 = *(const f32x4*)(ap + k0 + fk + 4);
    f32x4 cc0 = *(const f32x4*)(cp + k0 + fk);
    f32x4 cc1 = *(const f32x4*)(cp + k0 + fk + 4);
    bf16x8 af;
#pragma unroll
    for (int j = 0; j < 4; ++j) {
      float v = (float)av[j] * aa0[j] + cc0[j];
      af[j] = (__bf16)(1.0f / (1.0f + __expf(-v)));
    }
#pragma unroll
    for (int j = 0; j < 4; ++j) {
      float v = (float)av[4 + j] * aa1[j] + cc1[j];
      af[4 + j] = (__bf16)(1.0f / (1.0f + __expf(-v)));
    }
    bf16x8 b0 = *(const bf16x8*)(Wd + (size_t)fr * F_N + k0 + fk);
    bf16x8 b1 = *(const bf16x8*)(Wd + (size_t)(16 + fr) * F_N + k0 + fk);
    acc[0] = __builtin_amdgcn_mfma_f32_16x16x32_bf16(af, b0, acc[0], 0, 0, 0);
    acc[1] = __builtin_amdgcn_mfma_f32_16x16x32_bf16(af, b1, acc[1], 0, 0, 0);
  }
  const int cr = (lane >> 4) * 4, cc = lane & 15;
#pragma unroll
  for (int n = 0; n < 2; ++n)
#pragma unroll
    for (int r = 0; r < 4; ++r)
      out2[(size_t)(m0 + wave * 16 + cr + r) * NCOL2 + d * O_N + n * 16 + cc] =
          acc[n][r];
}

// ---------------- BN3 stats on out2 ----------------
__global__ __launch_bounds__(128) void k_stats3_partial(
    const float* __restrict__ out2, float* __restrict__ part) {
  int t = threadIdx.x, blk = blockIdx.x;
  float s = 0, q = 0;
  int r0 = blk * 128;
  for (int r = r0; r < r0 + 128; ++r) {
    float v = out2[(size_t)r * NCOL2 + t];
    s += v;
    q += v * v;
  }
  part[(size_t)blk * 256 + t] = s;
  part[(size_t)blk * 256 + 128 + t] = q;
}

__global__ __launch_bounds__(128) void k_stats3_final(
    const float* __restrict__ part, const float* __restrict__ g3,
    const float* __restrict__ b3, float* __restrict__ a3,
    float* __restrict__ c3) {
  int c = threadIdx.x;
  float s = 0, q = 0;
  for (int b = 0; b < 128; ++b) {
    s += part[(size_t)b * 256 + c];
    q += part[(size_t)b * 256 + 128 + c];
  }
  float mean = s * (1.0f / B_N);
  float var = q * (1.0f / B_N) - mean * mean;
  float rstd = rsqrtf(var + EPS);
  float aa = rstd * g3[c];
  a3[c] = aa;
  c3[c] = b3[c] - mean * aa;
}

// ---------------- final: out = sigmoid(out2*a3+c3) ----------------
__global__ __launch_bounds__(256) void k_final(const float* __restrict__ out2,
                                               const float* __restrict__ a3,
                                               const float* __restrict__ c3,
                                               float* __restrict__ out) {
  size_t base = (size_t)(blockIdx.x * 256 + threadIdx.x) * 4;
  int c = (int)(base & (NCOL2 - 1));
  f32x4 v = *(const f32x4*)(out2 + base);
  f32x4 a = *(const f32x4*)(a3 + c);
  f32x4 cc = *(const f32x4*)(c3 + c);
  f32x4 o;
#pragma unroll
  for (int j = 0; j < 4; ++j)
    o[j] = 1.0f / (1.0f + __expf(-(v[j] * a[j] + cc[j])));
  *(f32x4*)(out + base) = o;
}

extern "C" void kernel_launch(void* const* d_in, const int* in_sizes, int n_in,
                              void* d_out, int out_size, void* d_ws,
                              size_t ws_size, hipStream_t stream) {
  (void)in_sizes; (void)n_in; (void)out_size; (void)ws_size;
  const float* x = (const float*)d_in[0];
  const float* W1 = (const float*)d_in[1];
  const float* W2 = (const float*)d_in[2];
  const float* g1 = (const float*)d_in[3];
  // d_in[4] = b1: per-column constant after GEMM1, annihilated by BN2 mean-sub.
  const float* g2 = (const float*)d_in[5];
  const float* b2 = (const float*)d_in[6];
  const float* g3 = (const float*)d_in[7];
  const float* b3 = (const float*)d_in[8];
  float* out = (float*)d_out;

  char* ws = (char*)d_ws;
  size_t off = 0;
  auto alloc = [&](size_t bytes) -> void* {
    void* p = ws + off;
    off = (off + bytes + 255) & ~(size_t)255;
    return p;
  };
  float* rstdx = (float*)alloc((size_t)F_N * 4);
  float* a2 = (float*)alloc((size_t)NCOL1 * 4);
  float* c2 = (float*)alloc((size_t)NCOL1 * 4);
  float* a3 = (float*)alloc((size_t)NCOL2 * 4);
  float* c3 = (float*)alloc((size_t)NCOL2 * 4);
  float* part1 = (float*)alloc((size_t)256 * 2048 * 4);
  float* p2s = (float*)alloc((size_t)64 * NCOL1 * 4);
  float* p2q = (float*)alloc((size_t)64 * NCOL1 * 4);
  float* part3 = (float*)alloc((size_t)128 * 256 * 4);
  __bf16* W1b = (__bf16*)alloc((size_t)D_N * F_N * F_N * 2);
  __bf16* W2b = (__bf16*)alloc((size_t)D_N * O_N * F_N * 2);
  __bf16* xb = (__bf16*)alloc((size_t)B_N * F_N * 2);
  __bf16* G1 = (__bf16*)alloc((size_t)B_N * NCOL1 * 2);
  float* out2 = (float*)alloc((size_t)B_N * NCOL2 * 4);

  k_stats_x_conv<<<256, 256, 0, stream>>>(x, part1, xb);
  k_stats_x_final<<<4, 256, 0, stream>>>(part1, rstdx);
  k_fold_w1<<<4096, 256, 0, stream>>>(W1, g1, rstdx, W1b);
  k_fold_w2<<<128, 256, 0, stream>>>(W2, W2b);
  k_gemm1<<<1024, 512, 0, stream>>>(xb, W1b, G1, p2s, p2q);
  k_stats2_final<<<16, 256, 0, stream>>>(p2s, p2q, g2, b2, a2, c2);
  k_gemm2<<<dim3(256, 4), 256, 0, stream>>>(G1, W2b, a2, c2, out2);
  k_stats3_partial<<<128, 128, 0, stream>>>(out2, part3);
  k_stats3_final<<<1, 128, 0, stream>>>(part3, g3, b3, a3, c3);
  k_final<<<2048, 256, 0, stream>>>(out2, a3, c3, out);
}